// Round 2
// baseline (1057.854 us; speedup 1.0000x reference)
//
#include <hip/hip_runtime.h>
#include <hip/hip_bf16.h>

// ---------------------------------------------------------------------------
// ProjectedConjugatedCSPNet: LN -> edge MLP (gather+sinemb+2xGEMM+silu) ->
// scatter-mean -> node MLP (2xGEMM+silu) -> residual add.
// All GEMMs: bf16 MFMA 16x16x32, B pre-swizzled to fragment-linear order.
// R2: A-tile LDS stride 32->40 ushorts (kills 8-way ds_read_b128 conflicts),
//     hardware v_sin/v_cos in revolutions for sinemb, hoisted gather bases,
//     distinct kernel names per GEMM mode for rocprof attribution.
// ---------------------------------------------------------------------------

typedef __attribute__((ext_vector_type(8))) short bfrag;   // 8 bf16 = 4 VGPRs
typedef __attribute__((ext_vector_type(4))) float ffrag;   // 4 fp32 acc

#define DEVI __device__ __forceinline__

constexpr int N_NODES = 10000;
constexpr int N_EDGES = 200000;
constexpr int HD      = 512;    // hidden dim
constexpr int KE      = 1824;   // padded edge-K: 512 hi + 512 hj + 32 lat(pad) + 768 sinemb
constexpr int NT      = HD / 16; // 32 n-tiles of 16 cols
constexpr int ATS     = 40;     // A-tile LDS stride in ushorts (80B = 20 banks, 16B-aligned)

DEVI float silu_f(float v) { return v / (1.0f + __expf(-v)); }

DEVI ushort f2bf(float f) {
    unsigned u = __float_as_uint(f);
    unsigned r = (u + 0x7fffu + ((u >> 16) & 1u)) >> 16;
    return (ushort)r;
}

// ---------------- LayerNorm: node_features -> h (bf16) ----------------------
__global__ void ln_kernel(const float* __restrict__ x, const float* __restrict__ g,
                          const float* __restrict__ b, ushort* __restrict__ h) {
    __shared__ float wred[8];
    __shared__ float mb[2];
    int row = blockIdx.x;
    int t = threadIdx.x;              // 256 threads
    const float* xr = x + (size_t)row * HD;
    float x0 = xr[t], x1 = xr[t + 256];
    float s = x0 + x1, q = x0 * x0 + x1 * x1;
    for (int o = 32; o; o >>= 1) { s += __shfl_down(s, o); q += __shfl_down(q, o); }
    int w = t >> 6, l = t & 63;
    if (l == 0) { wred[w] = s; wred[w + 4] = q; }
    __syncthreads();
    if (t == 0) {
        float S = wred[0] + wred[1] + wred[2] + wred[3];
        float Q = wred[4] + wred[5] + wred[6] + wred[7];
        float m = S * (1.0f / HD);
        float v = Q * (1.0f / HD) - m * m;
        mb[0] = m; mb[1] = rsqrtf(v + 1e-5f);
    }
    __syncthreads();
    float m = mb[0], rs = mb[1];
    h[(size_t)row * HD + t]       = f2bf((x0 - m) * rs * g[t] + b[t]);
    h[(size_t)row * HD + t + 256] = f2bf((x1 - m) * rs * g[t + 256] + b[t + 256]);
}

// ------- Weight swizzle: W[K x 512] fp32 -> B-fragment-linear bf16 ----------
// dst frag layout: [((kk*NT + nn)*64 + lane)*8 + j] = W[32kk + 8*(lane>>4) + j][16nn + (lane&15)]
// mode 1 = W_e1 remap onto padded K=1824 layout (zero rows in lat pad).
__global__ void wswz_kernel(const float* __restrict__ W, ushort* __restrict__ dst,
                            int Kp, int mode) {
    int fid = blockIdx.x * blockDim.x + threadIdx.x;
    int total = (Kp / 32) * NT * 64;
    if (fid >= total) return;
    int l  = fid & 63;
    int nn = (fid >> 6) & 31;
    int kk = fid >> 11;
    int col = nn * 16 + (l & 15);
    int kb  = kk * 32 + (l >> 4) * 8;
    union { ushort u16[8]; uint4 u4; } v;
    for (int j = 0; j < 8; ++j) {
        int krow = kb + j;
        int src;
        if (mode == 1) {
            if (krow < 1024)      src = krow;            // hi | hj
            else if (krow < 1056) src = (krow - 1024) < 6 ? krow : -1;  // lat (pad->0)
            else                  src = krow - 26;       // sinemb: 1030 + (krow-1056)
        } else {
            src = krow;
        }
        float f = (src < 0) ? 0.0f : W[(size_t)src * HD + col];
        v.u16[j] = f2bf(f);
    }
    *(uint4*)(dst + (size_t)fid * 8) = v.u4;
}

// ---------------- agg/cnt -> bf16 (scatter-mean divide) ---------------------
__global__ void aggdiv_kernel(const float* __restrict__ agg, const float* __restrict__ cnt,
                              ushort* __restrict__ aggb) {
    int i = blockIdx.x * 256 + threadIdx.x;   // N_NODES*HD threads
    int row = i >> 9;
    float rc = 1.0f / fmaxf(cnt[row], 1.0f);
    aggb[i] = f2bf(agg[i] * rc);
}

__global__ void sentinel_kernel(float* o, int n) {
    int i = blockIdx.x * 256 + threadIdx.x;
    if (i < n) o[i] = 123456789.0f;
}

// ---------------- Unified MFMA GEMM body (64 rows x 512 cols per block) -----
// MODE 0: edge GEMM1  A = [gather(h,src) | gather(h,dst) | lat | sinemb], out = silu -> e1 bf16
// MODE 1: edge GEMM2  A = e1, epilogue = silu + atomic scatter into agg (+cnt)
// MODE 2: node GEMM1  A = [h | aggb], out = silu -> o1 bf16
// MODE 3: node GEMM2  A = o1, out = node_features + silu -> d_out fp32
template <int MODE>
DEVI void gemm_body(
    const ushort* __restrict__ Asrc1, const ushort* __restrict__ Asrc2,
    const ushort* __restrict__ Bswz,  const float* __restrict__ bias,
    ushort* __restrict__ outb,        float* __restrict__ outf,
    float* __restrict__ cnt,          const float* __restrict__ nf,
    const int* __restrict__ edge_index, const int* __restrict__ e2g,
    const float* __restrict__ lattices, const float* __restrict__ frac_diff,
    int KT) {

    __shared__ ushort At[64 * ATS];
    __shared__ int   ssrc[64];
    __shared__ int   sdst[64];
    __shared__ float sfd[64 * 3];
    __shared__ float slat[64 * 6];

    const int t = threadIdx.x;        // 512 threads = 8 waves
    const int w = t >> 6;
    const int l = t & 63;
    const int q = l >> 4;
    const int ml = l & 15;
    const int blk = blockIdx.x;
    const int rowbase = blk * 64;

    if (MODE == 0 || MODE == 1) {
        if (t < 64) {
            int eid = rowbase + t;
            int s = edge_index[eid];
            ssrc[t] = s;
            if (MODE == 0) {
                sdst[t] = edge_index[N_EDGES + eid];
                int g = e2g[eid];
                for (int c = 0; c < 6; ++c) slat[t * 6 + c] = lattices[g * 6 + c];
                for (int c = 0; c < 3; ++c) sfd[t * 3 + c] = frac_diff[(size_t)eid * 3 + c];
            }
        }
        __syncthreads();
    }

    ffrag acc[4][4];
    for (int m = 0; m < 4; ++m)
        for (int n = 0; n < 4; ++n)
            acc[m][n] = (ffrag){0.0f, 0.0f, 0.0f, 0.0f};

    const int r  = t >> 3;            // staging row 0..63
    const int c0 = (t & 7) * 4;       // staging col 0..28 step 4

    // hoisted per-thread staging state (constant across the K-loop)
    const ushort* pa = nullptr;       // gather base for src row (MODE 0) / linear row
    const ushort* pb = nullptr;       // gather base for dst row (MODE 0)
    float fdx = 0.f, fdy = 0.f, fdz = 0.f;
    if (MODE == 0) {
        pa = Asrc1 + (size_t)ssrc[r] * HD + c0;
        pb = Asrc1 + (size_t)sdst[r] * HD + c0;
        fdx = sfd[r * 3 + 0]; fdy = sfd[r * 3 + 1]; fdz = sfd[r * 3 + 2];
    }

    for (int kk = 0; kk < KT; ++kk) {
        // ---- stage A tile [64 x 32] bf16 ----
        ushort4 vals;
        if (MODE == 0) {
            if (kk < 32) {
                const ushort* hp = ((kk < 16) ? pa : pb) + (kk & 15) * 32;
                vals = *(const ushort4*)hp;
            } else if (kk == 32) {
                float f[4];
                for (int i = 0; i < 4; ++i) {
                    int c = c0 + i;
                    f[i] = (c < 6) ? slat[r * 6 + c] : 0.0f;
                }
                vals = make_ushort4(f2bf(f[0]), f2bf(f[1]), f2bf(f[2]), f2bf(f[3]));
            } else {
                // sinusoid embedding: sin/cos(2*pi*k*x) == v_sin/v_cos(fract(k*x)) [revolutions]
                int d0 = (kk - 33) * 32 + c0;           // 0..764, multiple of 4
                bool isc = d0 >= 384;
                int e0 = isc ? d0 - 384 : d0;
                int sdim = e0 >> 7;
                float x = (sdim == 0) ? fdx : (sdim == 1) ? fdy : fdz;
                float rev0 = (float)(e0 & 127) * x;
                float f[4];
                for (int i = 0; i < 4; ++i) {
                    float rv = __builtin_amdgcn_fractf(rev0 + (float)i * x);
                    f[i] = isc ? __builtin_amdgcn_cosf(rv) : __builtin_amdgcn_sinf(rv);
                }
                vals = make_ushort4(f2bf(f[0]), f2bf(f[1]), f2bf(f[2]), f2bf(f[3]));
            }
        } else if (MODE == 1) {
            vals = *(const ushort4*)(Asrc1 + (size_t)(rowbase + r) * HD + kk * 32 + c0);
        } else if (MODE == 2) {
            int row = rowbase + r;
            if (row < N_NODES) {
                const ushort* p = (kk < 16)
                    ? (Asrc1 + (size_t)row * HD + kk * 32 + c0)
                    : (Asrc2 + (size_t)row * HD + (kk - 16) * 32 + c0);
                vals = *(const ushort4*)p;
            } else vals = make_ushort4(0, 0, 0, 0);
        } else {
            int row = rowbase + r;
            vals = (row < N_NODES)
                ? *(const ushort4*)(Asrc1 + (size_t)row * HD + kk * 32 + c0)
                : make_ushort4(0, 0, 0, 0);
        }
        *(ushort4*)&At[r * ATS + c0] = vals;
        __syncthreads();

        // ---- fragments + MFMA ----
        bfrag af[4];
        for (int m = 0; m < 4; ++m)
            af[m] = *(const bfrag*)&At[(16 * m + ml) * ATS + q * 8];
        bfrag bf_[4];
        const ushort* bp = Bswz + ((size_t)(kk * NT + (w << 2)) * 64 + l) * 8;
        for (int n = 0; n < 4; ++n)
            bf_[n] = *(const bfrag*)(bp + (size_t)n * 64 * 8);
        for (int m = 0; m < 4; ++m)
            for (int n = 0; n < 4; ++n)
                acc[m][n] = __builtin_amdgcn_mfma_f32_16x16x32_bf16(af[m], bf_[n], acc[m][n], 0, 0, 0);
        __syncthreads();
    }

    // ---- epilogue ----
    if (MODE == 1 && t < 64) unsafeAtomicAdd(&cnt[ssrc[t]], 1.0f);

    for (int n = 0; n < 4; ++n) {
        int cg = w * 64 + n * 16 + ml;
        float bv = bias[cg];
        for (int m = 0; m < 4; ++m) {
            for (int rr = 0; rr < 4; ++rr) {
                int rowl = 16 * m + 4 * q + rr;
                float v = silu_f(acc[m][n][rr] + bv);
                if (MODE == 0) {
                    outb[(size_t)(rowbase + rowl) * HD + cg] = f2bf(v);
                } else if (MODE == 1) {
                    unsafeAtomicAdd(&outf[(size_t)ssrc[rowl] * HD + cg], v);
                } else if (MODE == 2) {
                    int row = rowbase + rowl;
                    if (row < N_NODES) outb[(size_t)row * HD + cg] = f2bf(v);
                } else {
                    int row = rowbase + rowl;
                    if (row < N_NODES)
                        outf[(size_t)row * HD + cg] = nf[(size_t)row * HD + cg] + v;
                }
            }
        }
    }
}

// distinct kernel names per mode for rocprof attribution
#define GEMM_ARGS \
    const ushort* __restrict__ Asrc1, const ushort* __restrict__ Asrc2, \
    const ushort* __restrict__ Bswz,  const float* __restrict__ bias, \
    ushort* __restrict__ outb,        float* __restrict__ outf, \
    float* __restrict__ cnt,          const float* __restrict__ nf, \
    const int* __restrict__ edge_index, const int* __restrict__ e2g, \
    const float* __restrict__ lattices, const float* __restrict__ frac_diff, \
    int KT
#define GEMM_PASS Asrc1, Asrc2, Bswz, bias, outb, outf, cnt, nf, edge_index, e2g, lattices, frac_diff, KT

__global__ __launch_bounds__(512, 2) void edge_gemm1(GEMM_ARGS) { gemm_body<0>(GEMM_PASS); }
__global__ __launch_bounds__(512, 2) void edge_gemm2(GEMM_ARGS) { gemm_body<1>(GEMM_PASS); }
__global__ __launch_bounds__(512, 2) void node_gemm1(GEMM_ARGS) { gemm_body<2>(GEMM_PASS); }
__global__ __launch_bounds__(512, 2) void node_gemm2(GEMM_ARGS) { gemm_body<3>(GEMM_PASS); }

// ---------------------------------------------------------------------------
extern "C" void kernel_launch(void* const* d_in, const int* in_sizes, int n_in,
                              void* d_out, int out_size, void* d_ws, size_t ws_size,
                              hipStream_t stream) {
    const float* nf      = (const float*)d_in[0];
    const float* latt    = (const float*)d_in[1];
    const int*   eidx    = (const int*)d_in[2];
    const int*   e2g     = (const int*)d_in[3];
    const float* fd      = (const float*)d_in[4];
    const float* ln_g    = (const float*)d_in[6];
    const float* ln_b    = (const float*)d_in[7];
    const float* W_e1    = (const float*)d_in[8];
    const float* b_e1    = (const float*)d_in[9];
    const float* W_e2    = (const float*)d_in[10];
    const float* b_e2    = (const float*)d_in[11];
    const float* W_n1    = (const float*)d_in[12];
    const float* b_n1    = (const float*)d_in[13];
    const float* W_n2    = (const float*)d_in[14];
    const float* b_n2    = (const float*)d_in[15];
    float* out = (float*)d_out;

    auto al = [](size_t x) { return (x + 511) & ~(size_t)511; };
    size_t off_h   = 0;                        size_t sz_h   = (size_t)N_NODES * HD * 2;
    size_t off_w1  = al(off_h + sz_h);         size_t sz_w1  = (size_t)KE * HD * 2;
    size_t off_w2  = al(off_w1 + sz_w1);       size_t sz_w2  = (size_t)HD * HD * 2;
    size_t off_wn1 = al(off_w2 + sz_w2);       size_t sz_wn1 = (size_t)2 * HD * HD * 2;
    size_t off_wn2 = al(off_wn1 + sz_wn1);     size_t sz_wn2 = (size_t)HD * HD * 2;
    size_t off_agg = al(off_wn2 + sz_wn2);     size_t sz_agg = (size_t)N_NODES * HD * 4;
    size_t off_cnt = al(off_agg + sz_agg);     size_t sz_cnt = (size_t)N_NODES * 4;
    size_t off_agb = al(off_cnt + sz_cnt);     size_t sz_agb = (size_t)N_NODES * HD * 2;
    size_t off_o1  = al(off_agb + sz_agb);     size_t sz_o1  = (size_t)N_NODES * HD * 2;
    size_t off_e1  = al(off_o1 + sz_o1);       size_t sz_e1  = (size_t)N_EDGES * HD * 2;
    size_t need    = off_e1 + sz_e1;

    if (ws_size < need) {
        sentinel_kernel<<<(out_size + 255) / 256, 256, 0, stream>>>(out, out_size);
        return;
    }

    char* ws = (char*)d_ws;
    ushort* h    = (ushort*)(ws + off_h);
    ushort* w1s  = (ushort*)(ws + off_w1);
    ushort* w2s  = (ushort*)(ws + off_w2);
    ushort* wn1s = (ushort*)(ws + off_wn1);
    ushort* wn2s = (ushort*)(ws + off_wn2);
    float*  agg  = (float*)(ws + off_agg);
    float*  cnt  = (float*)(ws + off_cnt);
    ushort* aggb = (ushort*)(ws + off_agb);
    ushort* o1   = (ushort*)(ws + off_o1);
    ushort* e1   = (ushort*)(ws + off_e1);

    // prep
    ln_kernel<<<N_NODES, 256, 0, stream>>>(nf, ln_g, ln_b, h);
    wswz_kernel<<<(KE / 32) * NT * 64 / 256, 256, 0, stream>>>(W_e1, w1s, KE, 1);
    wswz_kernel<<<(HD / 32) * NT * 64 / 256, 256, 0, stream>>>(W_e2, w2s, HD, 0);
    wswz_kernel<<<(2 * HD / 32) * NT * 64 / 256, 256, 0, stream>>>(W_n1, wn1s, 2 * HD, 0);
    wswz_kernel<<<(HD / 32) * NT * 64 / 256, 256, 0, stream>>>(W_n2, wn2s, HD, 0);
    hipMemsetAsync(agg, 0, sz_agg, stream);
    hipMemsetAsync(cnt, 0, sz_cnt, stream);

    // edge pipeline
    edge_gemm1<<<N_EDGES / 64, 512, 0, stream>>>(
        h, nullptr, w1s, b_e1, e1, nullptr, nullptr, nullptr,
        eidx, e2g, latt, fd, KE / 32);
    edge_gemm2<<<N_EDGES / 64, 512, 0, stream>>>(
        e1, nullptr, w2s, b_e2, nullptr, agg, cnt, nullptr,
        eidx, nullptr, nullptr, nullptr, HD / 32);

    // scatter-mean divide
    aggdiv_kernel<<<(N_NODES * HD) / 256, 256, 0, stream>>>(agg, cnt, aggb);

    // node pipeline
    int nblocks = (N_NODES + 63) / 64;
    node_gemm1<<<nblocks, 512, 0, stream>>>(
        h, aggb, wn1s, b_n1, o1, nullptr, nullptr, nullptr,
        nullptr, nullptr, nullptr, nullptr, 2 * HD / 32);
    node_gemm2<<<nblocks, 512, 0, stream>>>(
        o1, nullptr, wn2s, b_n2, nullptr, out, nullptr, nf,
        nullptr, nullptr, nullptr, nullptr, HD / 32);
}

// Round 3
// 1012.142 us; speedup vs baseline: 1.0452x; 1.0452x over previous
//
#include <hip/hip_runtime.h>
#include <hip/hip_bf16.h>

// ---------------------------------------------------------------------------
// ProjectedConjugatedCSPNet: LN -> edge MLP (gather+sinemb+2xGEMM+silu) ->
// scatter-mean -> node MLP (2xGEMM+silu) -> residual add.
// R3: slab-structured K-loops — global_load_lds DMAs whole gathered rows into
//     a 64x512 LDS slab (row stride 1040B), then 16 barrier-free ktiles of
//     MFMA; sinemb staged per-phase. Epilogue transposes through the slab for
//     coalesced b128 stores. Scatter-mean via CSR (hist+scan+fill+gather)
//     instead of 102M fp32 atomics; atomic path kept as ws-size fallback.
// ---------------------------------------------------------------------------

typedef __attribute__((ext_vector_type(8))) short bfrag;   // 8 bf16 = 4 VGPRs
typedef __attribute__((ext_vector_type(4))) float ffrag;   // 4 fp32 acc

#define DEVI __device__ __forceinline__

constexpr int N_NODES = 10000;
constexpr int N_EDGES = 200000;
constexpr int HD      = 512;     // hidden dim
constexpr int KE      = 1824;    // padded edge-K: 512 hi + 512 hj + 32 lat(pad) + 384 sin + 384 cos
constexpr int NT      = HD / 16; // 32 n-tiles of 16 cols
constexpr int SLABW   = 520;     // slab row stride in ushorts (1040 B: 16B-aligned, 2-way banks)

DEVI float silu_f(float v) { return v / (1.0f + __expf(-v)); }

DEVI ushort f2bf(float f) {
    unsigned u = __float_as_uint(f);
    unsigned r = (u + 0x7fffu + ((u >> 16) & 1u)) >> 16;
    return (ushort)r;
}
DEVI float bf2f(ushort v) { return __uint_as_float((unsigned)v << 16); }

DEVI void gll16(const ushort* gp, ushort* lp) {
    // global -> LDS DMA, 16B/lane. LDS side = wave-uniform base + lane*16;
    // global side is per-lane addressed (gather-capable).
    __builtin_amdgcn_global_load_lds((const __attribute__((address_space(1))) void*)gp,
                                     (__attribute__((address_space(3))) void*)lp, 16, 0, 0);
}

// ---------------- LayerNorm: node_features -> h (bf16) ----------------------
__global__ void ln_kernel(const float* __restrict__ x, const float* __restrict__ g,
                          const float* __restrict__ b, ushort* __restrict__ h) {
    __shared__ float wred[8];
    __shared__ float mb[2];
    int row = blockIdx.x;
    int t = threadIdx.x;              // 256 threads
    const float* xr = x + (size_t)row * HD;
    float x0 = xr[t], x1 = xr[t + 256];
    float s = x0 + x1, q = x0 * x0 + x1 * x1;
    for (int o = 32; o; o >>= 1) { s += __shfl_down(s, o); q += __shfl_down(q, o); }
    int w = t >> 6, l = t & 63;
    if (l == 0) { wred[w] = s; wred[w + 4] = q; }
    __syncthreads();
    if (t == 0) {
        float S = wred[0] + wred[1] + wred[2] + wred[3];
        float Q = wred[4] + wred[5] + wred[6] + wred[7];
        float m = S * (1.0f / HD);
        float v = Q * (1.0f / HD) - m * m;
        mb[0] = m; mb[1] = rsqrtf(v + 1e-5f);
    }
    __syncthreads();
    float m = mb[0], rs = mb[1];
    h[(size_t)row * HD + t]       = f2bf((x0 - m) * rs * g[t] + b[t]);
    h[(size_t)row * HD + t + 256] = f2bf((x1 - m) * rs * g[t + 256] + b[t + 256]);
}

// ------- Weight swizzle: W[K x 512] fp32 -> B-fragment-linear bf16 ----------
__global__ void wswz_kernel(const float* __restrict__ W, ushort* __restrict__ dst,
                            int Kp, int mode) {
    int fid = blockIdx.x * blockDim.x + threadIdx.x;
    int total = (Kp / 32) * NT * 64;
    if (fid >= total) return;
    int l  = fid & 63;
    int nn = (fid >> 6) & 31;
    int kk = fid >> 11;
    int col = nn * 16 + (l & 15);
    int kb  = kk * 32 + (l >> 4) * 8;
    union { ushort u16[8]; uint4 u4; } v;
    for (int j = 0; j < 8; ++j) {
        int krow = kb + j;
        int src;
        if (mode == 1) {
            if (krow < 1024)      src = krow;                            // hi | hj
            else if (krow < 1056) src = (krow - 1024) < 6 ? krow : -1;   // lat (pad->0)
            else                  src = krow - 26;                       // sin|cos: 1030 + (krow-1056)
        } else {
            src = krow;
        }
        float f = (src < 0) ? 0.0f : W[(size_t)src * HD + col];
        v.u16[j] = f2bf(f);
    }
    *(uint4*)(dst + (size_t)fid * 8) = v.u4;
}

// ---------------- CSR build -------------------------------------------------
__global__ void hist_kernel(const int* __restrict__ eidx, int* __restrict__ cnt32) {
    int e = blockIdx.x * 256 + threadIdx.x;
    if (e < N_EDGES) atomicAdd(&cnt32[eidx[e]], 1);
}

__global__ void scan_kernel(const int* __restrict__ cnt32, int* __restrict__ row_ptr,
                            int* __restrict__ cursor) {
    __shared__ int buf[1024];
    int t = threadIdx.x;              // 1024 threads
    int base = t * 10;
    int loc[10]; int s = 0;
    for (int i = 0; i < 10; ++i) {
        int idx = base + i;
        int v = (idx < N_NODES) ? cnt32[idx] : 0;
        loc[i] = s; s += v;
    }
    buf[t] = s; __syncthreads();
    for (int off = 1; off < 1024; off <<= 1) {
        int v = 0; if (t >= off) v = buf[t - off];
        __syncthreads();
        buf[t] += v; __syncthreads();
    }
    int excl = buf[t] - s;            // exclusive prefix
    for (int i = 0; i < 10; ++i) {
        int idx = base + i;
        if (idx < N_NODES) { int p = excl + loc[i]; row_ptr[idx] = p; cursor[idx] = p; }
    }
    if (t == 0) row_ptr[N_NODES] = N_EDGES;
}

__global__ void csr_fill(const int* __restrict__ eidx, int* __restrict__ cursor,
                         int* __restrict__ ebuf) {
    int e = blockIdx.x * 256 + threadIdx.x;
    if (e >= N_EDGES) return;
    int pos = atomicAdd(&cursor[eidx[e]], 1);
    ebuf[pos] = e;
}

// ---------------- CSR gather-mean: e2 rows -> aggb (bf16) -------------------
__global__ void agg_gather(const ushort* __restrict__ e2, const int* __restrict__ rp,
                           const int* __restrict__ ebuf, ushort* __restrict__ aggb) {
    __shared__ int el[256];
    int node = blockIdx.x;
    int t = threadIdx.x;              // 256 threads, 2 cols each
    int beg = rp[node], end = rp[node + 1];
    int deg = end - beg;
    float a0 = 0.f, a1 = 0.f;
    for (int base = 0; base < deg; base += 256) {
        int n = min(256, deg - base);
        if (t < n) el[t] = ebuf[beg + base + t];
        __syncthreads();
        for (int i = 0; i < n; ++i) {
            const ushort* p = e2 + (size_t)el[i] * HD + t * 2;
            ushort2 v = *(const ushort2*)p;
            a0 += bf2f(v.x); a1 += bf2f(v.y);
        }
        __syncthreads();
    }
    float rc = 1.0f / fmaxf((float)deg, 1.0f);
    ushort2 o; o.x = f2bf(a0 * rc); o.y = f2bf(a1 * rc);
    *(ushort2*)&aggb[(size_t)node * HD + t * 2] = o;
}

// ---------------- fallback: agg/cnt -> bf16 ---------------------------------
__global__ void aggdiv_kernel(const float* __restrict__ agg, const float* __restrict__ cnt,
                              ushort* __restrict__ aggb) {
    int i = blockIdx.x * 256 + threadIdx.x;
    int row = i >> 9;
    float rc = 1.0f / fmaxf(cnt[row], 1.0f);
    aggb[i] = f2bf(agg[i] * rc);
}

__global__ void sentinel_kernel(float* o, int n) {
    int i = blockIdx.x * 256 + threadIdx.x;
    if (i < n) o[i] = 123456789.0f;
}

// ---------------- Slab-structured MFMA GEMM (64 rows x 512 cols/block) ------
// MODE 0: edge GEMM1  A = [gather(h,src)|gather(h,dst)|lat|sin|cos] -> silu -> e1
// MODE 1: edge GEMM2  A = e1; ATOMIC? scatter-add agg(+cnt) : linear e2
// MODE 2: node GEMM1  A = [h | aggb] -> silu -> o1
// MODE 3: node GEMM2  A = o1 -> nf + silu -> out fp32
template <int MODE, bool ATOMIC>
DEVI void gemm_body(
    const ushort* __restrict__ Asrc1, const ushort* __restrict__ Asrc2,
    const ushort* __restrict__ Bswz,  const float* __restrict__ bias,
    ushort* __restrict__ outb,        float* __restrict__ outf,
    float* __restrict__ cntf,         const float* __restrict__ nf,
    const int* __restrict__ edge_index, const int* __restrict__ e2g,
    const float* __restrict__ lattices, const float* __restrict__ frac_diff) {

    __shared__ ushort slab[64 * SLABW];     // 66560 B
    __shared__ int   ssrc[64];
    __shared__ int   sdst[64];
    __shared__ float sfd[64 * 3];
    __shared__ float slat[64 * 6];

    const int t = threadIdx.x;        // 512 threads = 8 waves
    const int w = t >> 6;
    const int l = t & 63;
    const int q = l >> 4;
    const int ml = l & 15;
    const int rowbase = blockIdx.x * 64;

    if (MODE == 0) {
        if (t < 64) {
            int eid = rowbase + t;
            ssrc[t] = edge_index[eid];
            sdst[t] = edge_index[N_EDGES + eid];
            int g = e2g[eid];
            for (int c = 0; c < 6; ++c) slat[t * 6 + c] = lattices[g * 6 + c];
            for (int c = 0; c < 3; ++c) sfd[t * 3 + c] = frac_diff[(size_t)eid * 3 + c];
        }
        __syncthreads();
    }
    if (MODE == 1 && ATOMIC) {
        if (t < 64) ssrc[t] = edge_index[rowbase + t];
        __syncthreads();
    }

    ffrag acc[4][4];
    for (int m = 0; m < 4; ++m)
        for (int n = 0; n < 4; ++n)
            acc[m][n] = (ffrag){0.0f, 0.0f, 0.0f, 0.0f};

    // DMA 8 full rows per wave into the slab (1 KB contiguous per row).
    auto load_rows_gather = [&](const ushort* base, const int* rowsArr) {
        for (int j = 0; j < 8; ++j) {
            int r = w * 8 + j;
            const ushort* gp = base + (size_t)rowsArr[r] * HD + l * 8;
            gll16(gp, &slab[r * SLABW]);
        }
    };
    auto load_rows_lin = [&](const ushort* base) {
        for (int j = 0; j < 8; ++j) {
            int r = w * 8 + j;
            int row = rowbase + r;
            if (MODE >= 2 && row >= N_NODES) row = N_NODES - 1;
            const ushort* gp = base + (size_t)row * HD + l * 8;
            gll16(gp, &slab[r * SLABW]);
        }
    };
    // barrier-free ktile run over the slab; gbase = global ktile of slab col 0
    auto kloop = [&](int ntiles, int gbase) {
        for (int p = 0; p < ntiles; ++p) {
            bfrag af[4];
            for (int m = 0; m < 4; ++m)
                af[m] = *(const bfrag*)&slab[(16 * m + ml) * SLABW + p * 32 + q * 8];
            bfrag bf_[4];
            const ushort* bp = Bswz + ((size_t)((gbase + p) * NT + (w << 2)) * 64 + l) * 8;
            for (int n = 0; n < 4; ++n)
                bf_[n] = *(const bfrag*)(bp + (size_t)n * 64 * 8);
            for (int m = 0; m < 4; ++m)
                for (int n = 0; n < 4; ++n)
                    acc[m][n] = __builtin_amdgcn_mfma_f32_16x16x32_bf16(af[m], bf_[n], acc[m][n], 0, 0, 0);
        }
    };

    const int r  = t >> 3;            // staging row 0..63 (sinemb phases)
    const int c0 = (t & 7) * 4;       // staging col 0..28 step 4

    if (MODE == 0) {
        load_rows_gather(Asrc1, ssrc);       __syncthreads();
        kloop(16, 0);                        __syncthreads();
        load_rows_gather(Asrc1, sdst);       __syncthreads();
        kloop(16, 16);                       __syncthreads();
        // phase C1: lat(32 cols incl pad) + sin(384) = 416 cols = 13 ktiles
        {
            float fx = sfd[r * 3 + 0], fy = sfd[r * 3 + 1], fz = sfd[r * 3 + 2];
            for (int i = 0; i < 13; ++i) {
                int c = c0 + 32 * i;
                float f[4];
                if (c < 32) {
                    for (int ii = 0; ii < 4; ++ii) {
                        int cc = c + ii;
                        f[ii] = (cc < 6) ? slat[r * 6 + cc] : 0.0f;
                    }
                } else {
                    int d = c - 32;                    // 0..383
                    int dim = d >> 7;
                    float x = (dim == 0) ? fx : (dim == 1) ? fy : fz;
                    float base = (float)(d & 127) * x;
                    for (int ii = 0; ii < 4; ++ii)
                        f[ii] = __builtin_amdgcn_sinf(__builtin_amdgcn_fractf(base + (float)ii * x));
                }
                ushort4 v = make_ushort4(f2bf(f[0]), f2bf(f[1]), f2bf(f[2]), f2bf(f[3]));
                *(ushort4*)&slab[r * SLABW + c] = v;
            }
            __syncthreads();
            kloop(13, 32);                   __syncthreads();
            // phase C2: cos(384) = 12 ktiles
            for (int i = 0; i < 12; ++i) {
                int c = c0 + 32 * i;                   // 0..383
                int dim = c >> 7;
                float x = (dim == 0) ? fx : (dim == 1) ? fy : fz;
                float base = (float)(c & 127) * x;
                float f[4];
                for (int ii = 0; ii < 4; ++ii)
                    f[ii] = __builtin_amdgcn_cosf(__builtin_amdgcn_fractf(base + (float)ii * x));
                ushort4 v = make_ushort4(f2bf(f[0]), f2bf(f[1]), f2bf(f[2]), f2bf(f[3]));
                *(ushort4*)&slab[r * SLABW + c] = v;
            }
            __syncthreads();
            kloop(12, 45);
        }
    } else if (MODE == 1) {
        load_rows_lin(Asrc1);                __syncthreads();
        kloop(16, 0);
    } else if (MODE == 2) {
        load_rows_lin(Asrc1);                __syncthreads();
        kloop(16, 0);                        __syncthreads();
        load_rows_lin(Asrc2);                __syncthreads();
        kloop(16, 16);
    } else {
        load_rows_lin(Asrc1);                __syncthreads();
        kloop(16, 0);
    }

    // ---- epilogue ----
    if (MODE == 1 && ATOMIC) {
        if (t < 64) unsafeAtomicAdd(&cntf[ssrc[t]], 1.0f);
        for (int n = 0; n < 4; ++n) {
            int cg = w * 64 + n * 16 + ml;
            float bv = bias[cg];
            for (int m = 0; m < 4; ++m)
                for (int rr = 0; rr < 4; ++rr) {
                    int rowl = 16 * m + 4 * q + rr;
                    float v = silu_f(acc[m][n][rr] + bv);
                    unsafeAtomicAdd(&outf[(size_t)ssrc[rowl] * HD + cg], v);
                }
        }
        return;
    }
    if (MODE == 3) {
        for (int n = 0; n < 4; ++n) {
            int cg = w * 64 + n * 16 + ml;
            float bv = bias[cg];
            for (int m = 0; m < 4; ++m)
                for (int rr = 0; rr < 4; ++rr) {
                    int rowl = 16 * m + 4 * q + rr;
                    int row = rowbase + rowl;
                    if (row < N_NODES) {
                        float v = silu_f(acc[m][n][rr] + bv);
                        outf[(size_t)row * HD + cg] = nf[(size_t)row * HD + cg] + v;
                    }
                }
        }
        return;
    }
    // MODE 0/1(lin)/2: transpose through slab -> coalesced b128 row stores
    __syncthreads();
    for (int n = 0; n < 4; ++n) {
        int cg = w * 64 + n * 16 + ml;
        float bv = bias[cg];
        for (int m = 0; m < 4; ++m)
            for (int rr = 0; rr < 4; ++rr) {
                int rowl = 16 * m + 4 * q + rr;
                slab[rowl * SLABW + cg] = f2bf(silu_f(acc[m][n][rr] + bv));
            }
    }
    __syncthreads();
    for (int j = 0; j < 8; ++j) {
        int row = w * 8 + j;
        int grow = rowbase + row;
        if (MODE == 2 && grow >= N_NODES) break;
        uint4 v = *(const uint4*)&slab[row * SLABW + l * 8];
        *(uint4*)(outb + (size_t)grow * HD + l * 8) = v;
    }
}

#define GEMM_ARGS \
    const ushort* __restrict__ Asrc1, const ushort* __restrict__ Asrc2, \
    const ushort* __restrict__ Bswz,  const float* __restrict__ bias, \
    ushort* __restrict__ outb,        float* __restrict__ outf, \
    float* __restrict__ cntf,         const float* __restrict__ nf, \
    const int* __restrict__ edge_index, const int* __restrict__ e2g, \
    const float* __restrict__ lattices, const float* __restrict__ frac_diff
#define GEMM_PASS Asrc1, Asrc2, Bswz, bias, outb, outf, cntf, nf, edge_index, e2g, lattices, frac_diff

__global__ __launch_bounds__(512, 4) void edge_gemm1(GEMM_ARGS)     { gemm_body<0, false>(GEMM_PASS); }
__global__ __launch_bounds__(512, 4) void edge_gemm2_lin(GEMM_ARGS) { gemm_body<1, false>(GEMM_PASS); }
__global__ __launch_bounds__(512, 4) void edge_gemm2_atm(GEMM_ARGS) { gemm_body<1, true>(GEMM_PASS); }
__global__ __launch_bounds__(512, 4) void node_gemm1(GEMM_ARGS)     { gemm_body<2, false>(GEMM_PASS); }
__global__ __launch_bounds__(512, 4) void node_gemm2(GEMM_ARGS)     { gemm_body<3, false>(GEMM_PASS); }

// ---------------------------------------------------------------------------
extern "C" void kernel_launch(void* const* d_in, const int* in_sizes, int n_in,
                              void* d_out, int out_size, void* d_ws, size_t ws_size,
                              hipStream_t stream) {
    const float* nf      = (const float*)d_in[0];
    const float* latt    = (const float*)d_in[1];
    const int*   eidx    = (const int*)d_in[2];
    const int*   e2g     = (const int*)d_in[3];
    const float* fd      = (const float*)d_in[4];
    const float* ln_g    = (const float*)d_in[6];
    const float* ln_b    = (const float*)d_in[7];
    const float* W_e1    = (const float*)d_in[8];
    const float* b_e1    = (const float*)d_in[9];
    const float* W_e2    = (const float*)d_in[10];
    const float* b_e2    = (const float*)d_in[11];
    const float* W_n1    = (const float*)d_in[12];
    const float* b_n1    = (const float*)d_in[13];
    const float* W_n2    = (const float*)d_in[14];
    const float* b_n2    = (const float*)d_in[15];
    float* out = (float*)d_out;

    auto al = [](size_t x) { return (x + 511) & ~(size_t)511; };
    size_t off_h    = 0;                         size_t sz_h    = (size_t)N_NODES * HD * 2;
    size_t off_w1   = al(off_h + sz_h);          size_t sz_w1   = (size_t)KE * HD * 2;
    size_t off_w2   = al(off_w1 + sz_w1);        size_t sz_w2   = (size_t)HD * HD * 2;
    size_t off_wn1  = al(off_w2 + sz_w2);        size_t sz_wn1  = (size_t)2 * HD * HD * 2;
    size_t off_wn2  = al(off_wn1 + sz_wn1);      size_t sz_wn2  = (size_t)HD * HD * 2;
    size_t off_agb  = al(off_wn2 + sz_wn2);      size_t sz_agb  = (size_t)N_NODES * HD * 2;
    size_t off_o1   = al(off_agb + sz_agb);      size_t sz_o1   = (size_t)N_NODES * HD * 2;
    size_t off_cntf = al(off_o1 + sz_o1);        size_t sz_cntf = (size_t)N_NODES * 4;
    size_t off_c32  = al(off_cntf + sz_cntf);    size_t sz_c32  = (size_t)N_NODES * 4;
    size_t off_cur  = al(off_c32 + sz_c32);      size_t sz_cur  = (size_t)N_NODES * 4;
    size_t off_rp   = al(off_cur + sz_cur);      size_t sz_rp   = (size_t)(N_NODES + 1) * 4;
    size_t off_ebuf = al(off_rp + sz_rp);        size_t sz_ebuf = (size_t)N_EDGES * 4;
    size_t off_e1   = al(off_ebuf + sz_ebuf);    size_t sz_e1   = (size_t)N_EDGES * HD * 2;
    size_t off_un   = al(off_e1 + sz_e1);        // union: e2 (csr) | agg fp32 (fallback)
    size_t sz_e2    = (size_t)N_EDGES * HD * 2;
    size_t sz_agg   = (size_t)N_NODES * HD * 4;
    size_t need_fb  = off_un + sz_agg;
    size_t need_csr = off_un + sz_e2;

    if (ws_size < need_fb) {
        sentinel_kernel<<<(out_size + 255) / 256, 256, 0, stream>>>(out, out_size);
        return;
    }
    bool use_csr = ws_size >= need_csr;

    char* ws = (char*)d_ws;
    ushort* h    = (ushort*)(ws + off_h);
    ushort* w1s  = (ushort*)(ws + off_w1);
    ushort* w2s  = (ushort*)(ws + off_w2);
    ushort* wn1s = (ushort*)(ws + off_wn1);
    ushort* wn2s = (ushort*)(ws + off_wn2);
    ushort* aggb = (ushort*)(ws + off_agb);
    ushort* o1   = (ushort*)(ws + off_o1);
    float*  cntf = (float*)(ws + off_cntf);
    int*    c32  = (int*)(ws + off_c32);
    int*    cur  = (int*)(ws + off_cur);
    int*    rp   = (int*)(ws + off_rp);
    int*    ebuf = (int*)(ws + off_ebuf);
    ushort* e1   = (ushort*)(ws + off_e1);
    ushort* e2   = (ushort*)(ws + off_un);
    float*  agg  = (float*)(ws + off_un);

    // prep
    ln_kernel<<<N_NODES, 256, 0, stream>>>(nf, ln_g, ln_b, h);
    wswz_kernel<<<(KE / 32) * NT * 64 / 256, 256, 0, stream>>>(W_e1, w1s, KE, 1);
    wswz_kernel<<<(HD / 32) * NT * 64 / 256, 256, 0, stream>>>(W_e2, w2s, HD, 0);
    wswz_kernel<<<(2 * HD / 32) * NT * 64 / 256, 256, 0, stream>>>(W_n1, wn1s, 2 * HD, 0);
    wswz_kernel<<<(HD / 32) * NT * 64 / 256, 256, 0, stream>>>(W_n2, wn2s, HD, 0);

    // edge GEMM1
    edge_gemm1<<<N_EDGES / 64, 512, 0, stream>>>(
        h, nullptr, w1s, b_e1, e1, nullptr, nullptr, nullptr, eidx, e2g, latt, fd);

    if (use_csr) {
        hipMemsetAsync(c32, 0, sz_c32, stream);
        hist_kernel<<<(N_EDGES + 255) / 256, 256, 0, stream>>>(eidx, c32);
        scan_kernel<<<1, 1024, 0, stream>>>(c32, rp, cur);
        csr_fill<<<(N_EDGES + 255) / 256, 256, 0, stream>>>(eidx, cur, ebuf);
        edge_gemm2_lin<<<N_EDGES / 64, 512, 0, stream>>>(
            e1, nullptr, w2s, b_e2, e2, nullptr, nullptr, nullptr, eidx, nullptr, nullptr, nullptr);
        agg_gather<<<N_NODES, 256, 0, stream>>>(e2, rp, ebuf, aggb);
    } else {
        hipMemsetAsync(agg, 0, sz_agg, stream);
        hipMemsetAsync(cntf, 0, sz_cntf, stream);
        edge_gemm2_atm<<<N_EDGES / 64, 512, 0, stream>>>(
            e1, nullptr, w2s, b_e2, nullptr, agg, cntf, nullptr, eidx, nullptr, nullptr, nullptr);
        aggdiv_kernel<<<(N_NODES * HD) / 256, 256, 0, stream>>>(agg, cntf, aggb);
    }

    // node pipeline
    int nblocks = (N_NODES + 63) / 64;
    node_gemm1<<<nblocks, 512, 0, stream>>>(
        h, aggb, wn1s, b_n1, o1, nullptr, nullptr, nullptr, nullptr, nullptr, nullptr, nullptr);
    node_gemm2<<<nblocks, 512, 0, stream>>>(
        o1, nullptr, wn2s, b_n2, nullptr, out, nullptr, nf, nullptr, nullptr, nullptr, nullptr);
}

// Round 4
// 880.011 us; speedup vs baseline: 1.2021x; 1.1501x over previous
//
#include <hip/hip_runtime.h>
#include <hip/hip_bf16.h>

// ---------------------------------------------------------------------------
// ProjectedConjugatedCSPNet: LN -> edge MLP (gather+sinemb+2xGEMM+silu) ->
// scatter-mean -> node MLP (2xGEMM+silu) -> residual add.
// R4: CSR-ordered edge pipeline. Edges sorted by src (hist+scan+fill);
//     edge_gemm1 gathers via ebuf (src rows ~4 distinct/block -> L2-hot),
//     edge_gemm2 reads e1 linearly and does an in-epilogue run-length
//     segment-reduce over the CSR-sorted rows: ~6.7M coalesced atomics
//     instead of 102M. cnt comes from CSR degrees. nbuf aliases aggb
//     (disjoint lifetimes) to stay within the ~261MB proven ws budget.
// ---------------------------------------------------------------------------

typedef __attribute__((ext_vector_type(8))) short bfrag;   // 8 bf16 = 4 VGPRs
typedef __attribute__((ext_vector_type(4))) float ffrag;   // 4 fp32 acc

#define DEVI __device__ __forceinline__

constexpr int N_NODES = 10000;
constexpr int N_EDGES = 200000;
constexpr int HD      = 512;     // hidden dim
constexpr int KE      = 1824;    // padded edge-K: 512 hi + 512 hj + 32 lat(pad) + 384 sin + 384 cos
constexpr int NT      = HD / 16; // 32 n-tiles of 16 cols
constexpr int SLABW   = 520;     // slab row stride in ushorts (1040 B)

DEVI float silu_f(float v) { return v / (1.0f + __expf(-v)); }

DEVI ushort f2bf(float f) {
    unsigned u = __float_as_uint(f);
    unsigned r = (u + 0x7fffu + ((u >> 16) & 1u)) >> 16;
    return (ushort)r;
}
DEVI float bf2f(ushort v) { return __uint_as_float((unsigned)v << 16); }

DEVI void gll16(const ushort* gp, ushort* lp) {
    // global -> LDS DMA, 16B/lane. LDS side = wave-uniform base + lane*16;
    // global side is per-lane addressed (gather-capable).
    __builtin_amdgcn_global_load_lds((const __attribute__((address_space(1))) void*)gp,
                                     (__attribute__((address_space(3))) void*)lp, 16, 0, 0);
}

// ---------------- LayerNorm: node_features -> h (bf16) ----------------------
__global__ void ln_kernel(const float* __restrict__ x, const float* __restrict__ g,
                          const float* __restrict__ b, ushort* __restrict__ h) {
    __shared__ float wred[8];
    __shared__ float mb[2];
    int row = blockIdx.x;
    int t = threadIdx.x;              // 256 threads
    const float* xr = x + (size_t)row * HD;
    float x0 = xr[t], x1 = xr[t + 256];
    float s = x0 + x1, q = x0 * x0 + x1 * x1;
    for (int o = 32; o; o >>= 1) { s += __shfl_down(s, o); q += __shfl_down(q, o); }
    int w = t >> 6, l = t & 63;
    if (l == 0) { wred[w] = s; wred[w + 4] = q; }
    __syncthreads();
    if (t == 0) {
        float S = wred[0] + wred[1] + wred[2] + wred[3];
        float Q = wred[4] + wred[5] + wred[6] + wred[7];
        float m = S * (1.0f / HD);
        float v = Q * (1.0f / HD) - m * m;
        mb[0] = m; mb[1] = rsqrtf(v + 1e-5f);
    }
    __syncthreads();
    float m = mb[0], rs = mb[1];
    h[(size_t)row * HD + t]       = f2bf((x0 - m) * rs * g[t] + b[t]);
    h[(size_t)row * HD + t + 256] = f2bf((x1 - m) * rs * g[t + 256] + b[t + 256]);
}

// ------- Weight swizzle: W[K x 512] fp32 -> B-fragment-linear bf16 ----------
__global__ void wswz_kernel(const float* __restrict__ W, ushort* __restrict__ dst,
                            int Kp, int mode) {
    int fid = blockIdx.x * blockDim.x + threadIdx.x;
    int total = (Kp / 32) * NT * 64;
    if (fid >= total) return;
    int l  = fid & 63;
    int nn = (fid >> 6) & 31;
    int kk = fid >> 11;
    int col = nn * 16 + (l & 15);
    int kb  = kk * 32 + (l >> 4) * 8;
    union { ushort u16[8]; uint4 u4; } v;
    for (int j = 0; j < 8; ++j) {
        int krow = kb + j;
        int src;
        if (mode == 1) {
            if (krow < 1024)      src = krow;                            // hi | hj
            else if (krow < 1056) src = (krow - 1024) < 6 ? krow : -1;   // lat (pad->0)
            else                  src = krow - 26;                       // sin|cos: 1030 + (krow-1056)
        } else {
            src = krow;
        }
        float f = (src < 0) ? 0.0f : W[(size_t)src * HD + col];
        v.u16[j] = f2bf(f);
    }
    *(uint4*)(dst + (size_t)fid * 8) = v.u4;
}

// ---------------- CSR build -------------------------------------------------
__global__ void hist_kernel(const int* __restrict__ eidx, int* __restrict__ cnt32) {
    int e = blockIdx.x * 256 + threadIdx.x;
    if (e < N_EDGES) atomicAdd(&cnt32[eidx[e]], 1);
}

__global__ void scan_kernel(const int* __restrict__ cnt32, int* __restrict__ row_ptr,
                            int* __restrict__ cursor) {
    __shared__ int buf[1024];
    int t = threadIdx.x;              // 1024 threads
    int base = t * 10;
    int loc[10]; int s = 0;
    for (int i = 0; i < 10; ++i) {
        int idx = base + i;
        int v = (idx < N_NODES) ? cnt32[idx] : 0;
        loc[i] = s; s += v;
    }
    buf[t] = s; __syncthreads();
    for (int off = 1; off < 1024; off <<= 1) {
        int v = 0; if (t >= off) v = buf[t - off];
        __syncthreads();
        buf[t] += v; __syncthreads();
    }
    int excl = buf[t] - s;            // exclusive prefix
    for (int i = 0; i < 10; ++i) {
        int idx = base + i;
        if (idx < N_NODES) { int p = excl + loc[i]; row_ptr[idx] = p; cursor[idx] = p; }
    }
    if (t == 0) row_ptr[N_NODES] = N_EDGES;
}

__global__ void csr_fill(const int* __restrict__ eidx, int* __restrict__ cursor,
                         int* __restrict__ ebuf, int* __restrict__ nbuf) {
    int e = blockIdx.x * 256 + threadIdx.x;
    if (e >= N_EDGES) return;
    int n = eidx[e];
    int pos = atomicAdd(&cursor[n], 1);
    ebuf[pos] = e;
    nbuf[pos] = n;
}

// ---------------- agg (fp32) / deg -> aggb (bf16) ---------------------------
__global__ void aggdiv_kernel(const float* __restrict__ agg, const int* __restrict__ rp,
                              ushort* __restrict__ aggb) {
    int i = blockIdx.x * 256 + threadIdx.x;
    int row = i >> 9;
    int deg = rp[row + 1] - rp[row];
    float rc = 1.0f / (float)max(deg, 1);
    aggb[i] = f2bf(agg[i] * rc);
}

__global__ void sentinel_kernel(float* o, int n) {
    int i = blockIdx.x * 256 + threadIdx.x;
    if (i < n) o[i] = 123456789.0f;
}

// ---------------- Slab-structured MFMA GEMM (64 rows x 512 cols/block) ------
// MODE 0: edge GEMM1  A = [gather(h,src)|gather(h,dst)|lat|sin|cos] (CSR order) -> silu -> e1
// MODE 1: edge GEMM2  A = e1 (linear, CSR order); epilogue = silu + segment-reduce -> atomic agg
// MODE 2: node GEMM1  A = [h | aggb] -> silu -> o1
// MODE 3: node GEMM2  A = o1 -> nf + silu -> out fp32
template <int MODE>
DEVI void gemm_body(
    const ushort* __restrict__ Asrc1, const ushort* __restrict__ Asrc2,
    const ushort* __restrict__ Bswz,  const float* __restrict__ bias,
    ushort* __restrict__ outb,        float* __restrict__ outf,
    const float* __restrict__ nf,
    const int* __restrict__ edge_index, const int* __restrict__ e2g,
    const float* __restrict__ lattices, const float* __restrict__ frac_diff,
    const int* __restrict__ ebuf,     const int* __restrict__ nbuf) {

    __shared__ __align__(16) ushort slab[64 * SLABW];     // 66560 B (>= 64*256 fp32)
    __shared__ int   ssrc[64];
    __shared__ int   sdst[64];
    __shared__ float sfd[64 * 3];
    __shared__ float slat[64 * 6];

    const int t = threadIdx.x;        // 512 threads = 8 waves
    const int w = t >> 6;
    const int l = t & 63;
    const int q = l >> 4;
    const int ml = l & 15;
    const int rowbase = blockIdx.x * 64;

    if (MODE == 0) {
        if (t < 64) {
            int eid = ebuf[rowbase + t];
            ssrc[t] = edge_index[eid];
            sdst[t] = edge_index[N_EDGES + eid];
            int g = e2g[eid];
            for (int c = 0; c < 6; ++c) slat[t * 6 + c] = lattices[g * 6 + c];
            for (int c = 0; c < 3; ++c) sfd[t * 3 + c] = frac_diff[(size_t)eid * 3 + c];
        }
        __syncthreads();
    }
    if (MODE == 1) {
        if (t < 64) ssrc[t] = nbuf[rowbase + t];   // CSR node id per row (sorted)
        __syncthreads();
    }

    ffrag acc[4][4];
    for (int m = 0; m < 4; ++m)
        for (int n = 0; n < 4; ++n)
            acc[m][n] = (ffrag){0.0f, 0.0f, 0.0f, 0.0f};

    // DMA 8 full rows per wave into the slab (1 KB contiguous per row).
    auto load_rows_gather = [&](const ushort* base, const int* rowsArr) {
        for (int j = 0; j < 8; ++j) {
            int r = w * 8 + j;
            const ushort* gp = base + (size_t)rowsArr[r] * HD + l * 8;
            gll16(gp, &slab[r * SLABW]);
        }
    };
    auto load_rows_lin = [&](const ushort* base) {
        for (int j = 0; j < 8; ++j) {
            int r = w * 8 + j;
            int row = rowbase + r;
            if (MODE >= 2 && row >= N_NODES) row = N_NODES - 1;
            const ushort* gp = base + (size_t)row * HD + l * 8;
            gll16(gp, &slab[r * SLABW]);
        }
    };
    // barrier-free ktile run over the slab; gbase = global ktile of slab col 0
    auto kloop = [&](int ntiles, int gbase) {
        for (int p = 0; p < ntiles; ++p) {
            bfrag af[4];
            for (int m = 0; m < 4; ++m)
                af[m] = *(const bfrag*)&slab[(16 * m + ml) * SLABW + p * 32 + q * 8];
            bfrag bf_[4];
            const ushort* bp = Bswz + ((size_t)((gbase + p) * NT + (w << 2)) * 64 + l) * 8;
            for (int n = 0; n < 4; ++n)
                bf_[n] = *(const bfrag*)(bp + (size_t)n * 64 * 8);
            for (int m = 0; m < 4; ++m)
                for (int n = 0; n < 4; ++n)
                    acc[m][n] = __builtin_amdgcn_mfma_f32_16x16x32_bf16(af[m], bf_[n], acc[m][n], 0, 0, 0);
        }
    };

    const int r  = t >> 3;            // staging row 0..63 (sinemb phases)
    const int c0 = (t & 7) * 4;       // staging col 0..28 step 4

    if (MODE == 0) {
        load_rows_gather(Asrc1, ssrc);       __syncthreads();
        kloop(16, 0);                        __syncthreads();
        load_rows_gather(Asrc1, sdst);       __syncthreads();
        kloop(16, 16);                       __syncthreads();
        // phase C1: lat(32 cols incl pad) + sin(384) = 416 cols = 13 ktiles
        {
            float fx = sfd[r * 3 + 0], fy = sfd[r * 3 + 1], fz = sfd[r * 3 + 2];
            for (int i = 0; i < 13; ++i) {
                int c = c0 + 32 * i;
                float f[4];
                if (c < 32) {
                    for (int ii = 0; ii < 4; ++ii) {
                        int cc = c + ii;
                        f[ii] = (cc < 6) ? slat[r * 6 + cc] : 0.0f;
                    }
                } else {
                    int d = c - 32;                    // 0..383
                    int dim = d >> 7;
                    float x = (dim == 0) ? fx : (dim == 1) ? fy : fz;
                    float base = (float)(d & 127) * x;
                    for (int ii = 0; ii < 4; ++ii)
                        f[ii] = __builtin_amdgcn_sinf(__builtin_amdgcn_fractf(base + (float)ii * x));
                }
                ushort4 v = make_ushort4(f2bf(f[0]), f2bf(f[1]), f2bf(f[2]), f2bf(f[3]));
                *(ushort4*)&slab[r * SLABW + c] = v;
            }
            __syncthreads();
            kloop(13, 32);                   __syncthreads();
            // phase C2: cos(384) = 12 ktiles
            for (int i = 0; i < 12; ++i) {
                int c = c0 + 32 * i;                   // 0..383
                int dim = c >> 7;
                float x = (dim == 0) ? fx : (dim == 1) ? fy : fz;
                float base = (float)(c & 127) * x;
                float f[4];
                for (int ii = 0; ii < 4; ++ii)
                    f[ii] = __builtin_amdgcn_cosf(__builtin_amdgcn_fractf(base + (float)ii * x));
                ushort4 v = make_ushort4(f2bf(f[0]), f2bf(f[1]), f2bf(f[2]), f2bf(f[3]));
                *(ushort4*)&slab[r * SLABW + c] = v;
            }
            __syncthreads();
            kloop(12, 45);
        }
    } else if (MODE == 1) {
        load_rows_lin(Asrc1);                __syncthreads();
        kloop(16, 0);
    } else if (MODE == 2) {
        load_rows_lin(Asrc1);                __syncthreads();
        kloop(16, 0);                        __syncthreads();
        load_rows_lin(Asrc2);                __syncthreads();
        kloop(16, 16);
    } else {
        load_rows_lin(Asrc1);                __syncthreads();
        kloop(16, 0);
    }

    // ---- epilogue ----
    if (MODE == 1) {
        // silu -> fp32 LDS (two 256-col halves) -> run-length segment reduce
        // down the 64 CSR-sorted rows -> one atomicAdd per (segment, col).
        float* fs = (float*)slab;            // 64 x 256 fp32 = 65536 B
        for (int hh = 0; hh < 2; ++hh) {
            __syncthreads();
            if ((w >> 2) == hh) {
                for (int n = 0; n < 4; ++n) {
                    int cg = w * 64 + n * 16 + ml;
                    int lc = cg - hh * 256;
                    float bv = bias[cg];
                    for (int m = 0; m < 4; ++m)
                        for (int rr = 0; rr < 4; ++rr) {
                            int rowl = 16 * m + 4 * q + rr;
                            fs[rowl * 256 + lc] = silu_f(acc[m][n][rr] + bv);
                        }
                }
            }
            __syncthreads();
            if (t < 256) {
                int col = hh * 256 + t;
                int cur = ssrc[0];
                float run = 0.f;
                for (int rr2 = 0; rr2 < 64; ++rr2) {
                    int nd = ssrc[rr2];
                    if (nd != cur) {
                        unsafeAtomicAdd(&outf[(size_t)cur * HD + col], run);
                        run = 0.f; cur = nd;
                    }
                    run += fs[rr2 * 256 + t];
                }
                unsafeAtomicAdd(&outf[(size_t)cur * HD + col], run);
            }
        }
        return;
    }
    if (MODE == 3) {
        for (int n = 0; n < 4; ++n) {
            int cg = w * 64 + n * 16 + ml;
            float bv = bias[cg];
            for (int m = 0; m < 4; ++m)
                for (int rr = 0; rr < 4; ++rr) {
                    int rowl = 16 * m + 4 * q + rr;
                    int row = rowbase + rowl;
                    if (row < N_NODES) {
                        float v = silu_f(acc[m][n][rr] + bv);
                        outf[(size_t)row * HD + cg] = nf[(size_t)row * HD + cg] + v;
                    }
                }
        }
        return;
    }
    // MODE 0/2: transpose through slab -> coalesced b128 row stores
    __syncthreads();
    for (int n = 0; n < 4; ++n) {
        int cg = w * 64 + n * 16 + ml;
        float bv = bias[cg];
        for (int m = 0; m < 4; ++m)
            for (int rr = 0; rr < 4; ++rr) {
                int rowl = 16 * m + 4 * q + rr;
                slab[rowl * SLABW + cg] = f2bf(silu_f(acc[m][n][rr] + bv));
            }
    }
    __syncthreads();
    for (int j = 0; j < 8; ++j) {
        int row = w * 8 + j;
        int grow = rowbase + row;
        if (MODE == 2 && grow >= N_NODES) break;
        uint4 v = *(const uint4*)&slab[row * SLABW + l * 8];
        *(uint4*)(outb + (size_t)grow * HD + l * 8) = v;
    }
}

#define GEMM_ARGS \
    const ushort* __restrict__ Asrc1, const ushort* __restrict__ Asrc2, \
    const ushort* __restrict__ Bswz,  const float* __restrict__ bias, \
    ushort* __restrict__ outb,        float* __restrict__ outf, \
    const float* __restrict__ nf, \
    const int* __restrict__ edge_index, const int* __restrict__ e2g, \
    const float* __restrict__ lattices, const float* __restrict__ frac_diff, \
    const int* __restrict__ ebuf,     const int* __restrict__ nbuf
#define GEMM_PASS Asrc1, Asrc2, Bswz, bias, outb, outf, nf, edge_index, e2g, lattices, frac_diff, ebuf, nbuf

__global__ __launch_bounds__(512, 4) void edge_gemm1(GEMM_ARGS) { gemm_body<0>(GEMM_PASS); }
__global__ __launch_bounds__(512, 4) void edge_gemm2(GEMM_ARGS) { gemm_body<1>(GEMM_PASS); }
__global__ __launch_bounds__(512, 4) void node_gemm1(GEMM_ARGS) { gemm_body<2>(GEMM_PASS); }
__global__ __launch_bounds__(512, 4) void node_gemm2(GEMM_ARGS) { gemm_body<3>(GEMM_PASS); }

// ---------------------------------------------------------------------------
extern "C" void kernel_launch(void* const* d_in, const int* in_sizes, int n_in,
                              void* d_out, int out_size, void* d_ws, size_t ws_size,
                              hipStream_t stream) {
    const float* nf      = (const float*)d_in[0];
    const float* latt    = (const float*)d_in[1];
    const int*   eidx    = (const int*)d_in[2];
    const int*   e2g     = (const int*)d_in[3];
    const float* fd      = (const float*)d_in[4];
    const float* ln_g    = (const float*)d_in[6];
    const float* ln_b    = (const float*)d_in[7];
    const float* W_e1    = (const float*)d_in[8];
    const float* b_e1    = (const float*)d_in[9];
    const float* W_e2    = (const float*)d_in[10];
    const float* b_e2    = (const float*)d_in[11];
    const float* W_n1    = (const float*)d_in[12];
    const float* b_n1    = (const float*)d_in[13];
    const float* W_n2    = (const float*)d_in[14];
    const float* b_n2    = (const float*)d_in[15];
    float* out = (float*)d_out;

    auto al = [](size_t x) { return (x + 511) & ~(size_t)511; };
    size_t off_h    = 0;                         size_t sz_h    = (size_t)N_NODES * HD * 2;
    size_t off_w1   = al(off_h + sz_h);          size_t sz_w1   = (size_t)KE * HD * 2;
    size_t off_w2   = al(off_w1 + sz_w1);        size_t sz_w2   = (size_t)HD * HD * 2;
    size_t off_wn1  = al(off_w2 + sz_w2);        size_t sz_wn1  = (size_t)2 * HD * HD * 2;
    size_t off_wn2  = al(off_wn1 + sz_wn1);      size_t sz_wn2  = (size_t)HD * HD * 2;
    size_t off_agb  = al(off_wn2 + sz_wn2);      size_t sz_agb  = (size_t)N_NODES * HD * 2;  // nbuf aliases here
    size_t off_o1   = al(off_agb + sz_agb);      size_t sz_o1   = (size_t)N_NODES * HD * 2;
    size_t off_c32  = al(off_o1 + sz_o1);        size_t sz_c32  = (size_t)N_NODES * 4;
    size_t off_cur  = al(off_c32 + sz_c32);      size_t sz_cur  = (size_t)N_NODES * 4;
    size_t off_rp   = al(off_cur + sz_cur);      size_t sz_rp   = (size_t)(N_NODES + 1) * 4;
    size_t off_ebuf = al(off_rp + sz_rp);        size_t sz_ebuf = (size_t)N_EDGES * 4;
    size_t off_e1   = al(off_ebuf + sz_ebuf);    size_t sz_e1   = (size_t)N_EDGES * HD * 2;
    size_t off_agg  = al(off_e1 + sz_e1);        size_t sz_agg  = (size_t)N_NODES * HD * 4;
    size_t need     = off_agg + sz_agg;

    if (ws_size < need) {
        sentinel_kernel<<<(out_size + 255) / 256, 256, 0, stream>>>(out, out_size);
        return;
    }

    char* ws = (char*)d_ws;
    ushort* h    = (ushort*)(ws + off_h);
    ushort* w1s  = (ushort*)(ws + off_w1);
    ushort* w2s  = (ushort*)(ws + off_w2);
    ushort* wn1s = (ushort*)(ws + off_wn1);
    ushort* wn2s = (ushort*)(ws + off_wn2);
    ushort* aggb = (ushort*)(ws + off_agb);
    int*    nbuf = (int*)(ws + off_agb);          // alias: dead before aggdiv writes aggb
    ushort* o1   = (ushort*)(ws + off_o1);
    int*    c32  = (int*)(ws + off_c32);
    int*    cur  = (int*)(ws + off_cur);
    int*    rp   = (int*)(ws + off_rp);
    int*    ebuf = (int*)(ws + off_ebuf);
    ushort* e1   = (ushort*)(ws + off_e1);
    float*  agg  = (float*)(ws + off_agg);

    // prep
    ln_kernel<<<N_NODES, 256, 0, stream>>>(nf, ln_g, ln_b, h);
    wswz_kernel<<<(KE / 32) * NT * 64 / 256, 256, 0, stream>>>(W_e1, w1s, KE, 1);
    wswz_kernel<<<(HD / 32) * NT * 64 / 256, 256, 0, stream>>>(W_e2, w2s, HD, 0);
    wswz_kernel<<<(2 * HD / 32) * NT * 64 / 256, 256, 0, stream>>>(W_n1, wn1s, 2 * HD, 0);
    wswz_kernel<<<(HD / 32) * NT * 64 / 256, 256, 0, stream>>>(W_n2, wn2s, HD, 0);
    hipMemsetAsync(c32, 0, sz_c32, stream);
    hipMemsetAsync(agg, 0, sz_agg, stream);

    // CSR build (edges sorted by src node)
    hist_kernel<<<(N_EDGES + 255) / 256, 256, 0, stream>>>(eidx, c32);
    scan_kernel<<<1, 1024, 0, stream>>>(c32, rp, cur);
    csr_fill<<<(N_EDGES + 255) / 256, 256, 0, stream>>>(eidx, cur, ebuf, nbuf);

    // edge pipeline (CSR order)
    edge_gemm1<<<N_EDGES / 64, 512, 0, stream>>>(
        h, nullptr, w1s, b_e1, e1, nullptr, nullptr, eidx, e2g, latt, fd, ebuf, nbuf);
    edge_gemm2<<<N_EDGES / 64, 512, 0, stream>>>(
        e1, nullptr, w2s, b_e2, nullptr, agg, nullptr, eidx, nullptr, nullptr, nullptr, ebuf, nbuf);

    // scatter-mean divide (deg from CSR)
    aggdiv_kernel<<<(N_NODES * HD) / 256, 256, 0, stream>>>(agg, rp, aggb);

    // node pipeline
    int nblocks = (N_NODES + 63) / 64;
    node_gemm1<<<nblocks, 512, 0, stream>>>(
        h, aggb, wn1s, b_n1, o1, nullptr, nullptr, nullptr, nullptr, nullptr, nullptr, nullptr, nullptr);
    node_gemm2<<<nblocks, 512, 0, stream>>>(
        o1, nullptr, wn2s, b_n2, nullptr, out, nf, nullptr, nullptr, nullptr, nullptr, nullptr, nullptr);
}

// Round 5
// 719.053 us; speedup vs baseline: 1.4712x; 1.2238x over previous
//
#include <hip/hip_runtime.h>
#include <hip/hip_bf16.h>

// ---------------------------------------------------------------------------
// ProjectedConjugatedCSPNet: LN -> edge MLP (gather+sinemb+2xGEMM+silu) ->
// scatter-mean -> node MLP (2xGEMM+silu) -> residual add.
// R5: FUSED MLPs. edge_mlp = gemm1 (4-phase slab K-loop) -> silu into slab
//     -> gemm2 straight out of the slab -> silu + CSR run-length segment-
//     reduce -> ~6.7M coalesced atomics. Kills the 205MB e1 intermediate
//     (write+read) and one 3125-block launch. node_mlp fused the same way
//     (o1 lives in the slab). ws need drops to ~50 MB.
// ---------------------------------------------------------------------------

typedef __attribute__((ext_vector_type(8))) short bfrag;   // 8 bf16 = 4 VGPRs
typedef __attribute__((ext_vector_type(4))) float ffrag;   // 4 fp32 acc

#define DEVI __device__ __forceinline__

constexpr int N_NODES = 10000;
constexpr int N_EDGES = 200000;
constexpr int HD      = 512;     // hidden dim
constexpr int KE      = 1824;    // padded edge-K: 512 hi + 512 hj + 32 lat(pad) + 384 sin + 384 cos
constexpr int NT      = HD / 16; // 32 n-tiles of 16 cols
constexpr int SLABW   = 520;     // slab row stride in ushorts (1040 B)

DEVI float silu_f(float v) { return v / (1.0f + __expf(-v)); }

DEVI ushort f2bf(float f) {
    unsigned u = __float_as_uint(f);
    unsigned r = (u + 0x7fffu + ((u >> 16) & 1u)) >> 16;
    return (ushort)r;
}
DEVI float bf2f(ushort v) { return __uint_as_float((unsigned)v << 16); }

DEVI void gll16(const ushort* gp, ushort* lp) {
    // global -> LDS DMA, 16B/lane. LDS side = wave-uniform base + lane*16;
    // global side is per-lane addressed (gather-capable).
    __builtin_amdgcn_global_load_lds((const __attribute__((address_space(1))) void*)gp,
                                     (__attribute__((address_space(3))) void*)lp, 16, 0, 0);
}

// ---------------- LayerNorm: node_features -> h (bf16) ----------------------
__global__ void ln_kernel(const float* __restrict__ x, const float* __restrict__ g,
                          const float* __restrict__ b, ushort* __restrict__ h) {
    __shared__ float wred[8];
    __shared__ float mb[2];
    int row = blockIdx.x;
    int t = threadIdx.x;              // 256 threads
    const float* xr = x + (size_t)row * HD;
    float x0 = xr[t], x1 = xr[t + 256];
    float s = x0 + x1, q = x0 * x0 + x1 * x1;
    for (int o = 32; o; o >>= 1) { s += __shfl_down(s, o); q += __shfl_down(q, o); }
    int w = t >> 6, l = t & 63;
    if (l == 0) { wred[w] = s; wred[w + 4] = q; }
    __syncthreads();
    if (t == 0) {
        float S = wred[0] + wred[1] + wred[2] + wred[3];
        float Q = wred[4] + wred[5] + wred[6] + wred[7];
        float m = S * (1.0f / HD);
        float v = Q * (1.0f / HD) - m * m;
        mb[0] = m; mb[1] = rsqrtf(v + 1e-5f);
    }
    __syncthreads();
    float m = mb[0], rs = mb[1];
    h[(size_t)row * HD + t]       = f2bf((x0 - m) * rs * g[t] + b[t]);
    h[(size_t)row * HD + t + 256] = f2bf((x1 - m) * rs * g[t + 256] + b[t + 256]);
}

// ------- Weight swizzle: W[K x 512] fp32 -> B-fragment-linear bf16 ----------
__global__ void wswz_kernel(const float* __restrict__ W, ushort* __restrict__ dst,
                            int Kp, int mode) {
    int fid = blockIdx.x * blockDim.x + threadIdx.x;
    int total = (Kp / 32) * NT * 64;
    if (fid >= total) return;
    int l  = fid & 63;
    int nn = (fid >> 6) & 31;
    int kk = fid >> 11;
    int col = nn * 16 + (l & 15);
    int kb  = kk * 32 + (l >> 4) * 8;
    union { ushort u16[8]; uint4 u4; } v;
    for (int j = 0; j < 8; ++j) {
        int krow = kb + j;
        int src;
        if (mode == 1) {
            if (krow < 1024)      src = krow;                            // hi | hj
            else if (krow < 1056) src = (krow - 1024) < 6 ? krow : -1;   // lat (pad->0)
            else                  src = krow - 26;                       // sin|cos: 1030 + (krow-1056)
        } else {
            src = krow;
        }
        float f = (src < 0) ? 0.0f : W[(size_t)src * HD + col];
        v.u16[j] = f2bf(f);
    }
    *(uint4*)(dst + (size_t)fid * 8) = v.u4;
}

// ---------------- CSR build -------------------------------------------------
__global__ void hist_kernel(const int* __restrict__ eidx, int* __restrict__ cnt32) {
    int e = blockIdx.x * 256 + threadIdx.x;
    if (e < N_EDGES) atomicAdd(&cnt32[eidx[e]], 1);
}

__global__ void scan_kernel(const int* __restrict__ cnt32, int* __restrict__ row_ptr,
                            int* __restrict__ cursor) {
    __shared__ int buf[1024];
    int t = threadIdx.x;              // 1024 threads
    int base = t * 10;
    int loc[10]; int s = 0;
    for (int i = 0; i < 10; ++i) {
        int idx = base + i;
        int v = (idx < N_NODES) ? cnt32[idx] : 0;
        loc[i] = s; s += v;
    }
    buf[t] = s; __syncthreads();
    for (int off = 1; off < 1024; off <<= 1) {
        int v = 0; if (t >= off) v = buf[t - off];
        __syncthreads();
        buf[t] += v; __syncthreads();
    }
    int excl = buf[t] - s;            // exclusive prefix
    for (int i = 0; i < 10; ++i) {
        int idx = base + i;
        if (idx < N_NODES) { int p = excl + loc[i]; row_ptr[idx] = p; cursor[idx] = p; }
    }
    if (t == 0) row_ptr[N_NODES] = N_EDGES;
}

__global__ void csr_fill(const int* __restrict__ eidx, int* __restrict__ cursor,
                         int* __restrict__ ebuf) {
    int e = blockIdx.x * 256 + threadIdx.x;
    if (e >= N_EDGES) return;
    int pos = atomicAdd(&cursor[eidx[e]], 1);
    ebuf[pos] = e;
}

// ---------------- agg (fp32) / deg -> aggb (bf16) ---------------------------
__global__ void aggdiv_kernel(const float* __restrict__ agg, const int* __restrict__ rp,
                              ushort* __restrict__ aggb) {
    int i = blockIdx.x * 256 + threadIdx.x;
    int row = i >> 9;
    int deg = rp[row + 1] - rp[row];
    float rc = 1.0f / (float)max(deg, 1);
    aggb[i] = f2bf(agg[i] * rc);
}

__global__ void sentinel_kernel(float* o, int n) {
    int i = blockIdx.x * 256 + threadIdx.x;
    if (i < n) o[i] = 123456789.0f;
}

// ---------------- Fused edge MLP (64 edges x 512 cols per block) ------------
// A = [gather(h,src)|gather(h,dst)|lat|sin|cos] (CSR order) -> silu -> slab
// -> GEMM2 from slab -> silu -> CSR run-length segment reduce -> atomic agg.
__global__ __launch_bounds__(512, 4) void edge_mlp(
    const ushort* __restrict__ h,     const ushort* __restrict__ w1s,
    const ushort* __restrict__ w2s,   const float* __restrict__ b1,
    const float* __restrict__ b2,     float* __restrict__ agg,
    const int* __restrict__ edge_index, const int* __restrict__ e2g,
    const float* __restrict__ lattices, const float* __restrict__ frac_diff,
    const int* __restrict__ ebuf) {

    __shared__ __align__(16) ushort slab[64 * SLABW];     // 66560 B (>= 64*256 fp32)
    __shared__ int   ssrc[64];
    __shared__ int   sdst[64];
    __shared__ float sfd[64 * 3];
    __shared__ float slat[64 * 6];

    const int t = threadIdx.x;        // 512 threads = 8 waves
    const int w = t >> 6;
    const int l = t & 63;
    const int q = l >> 4;
    const int ml = l & 15;
    const int rowbase = blockIdx.x * 64;

    if (t < 64) {
        int eid = ebuf[rowbase + t];
        ssrc[t] = edge_index[eid];
        sdst[t] = edge_index[N_EDGES + eid];
        int g = e2g[eid];
        for (int c = 0; c < 6; ++c) slat[t * 6 + c] = lattices[g * 6 + c];
        for (int c = 0; c < 3; ++c) sfd[t * 3 + c] = frac_diff[(size_t)eid * 3 + c];
    }
    __syncthreads();

    ffrag acc[4][4];
    for (int m = 0; m < 4; ++m)
        for (int n = 0; n < 4; ++n)
            acc[m][n] = (ffrag){0.0f, 0.0f, 0.0f, 0.0f};

    auto load_rows_gather = [&](const int* rowsArr) {
        for (int j = 0; j < 8; ++j) {
            int r = w * 8 + j;
            const ushort* gp = h + (size_t)rowsArr[r] * HD + l * 8;
            gll16(gp, &slab[r * SLABW]);
        }
    };
    auto kloop = [&](const ushort* Bswz, int ntiles, int gbase) {
        for (int p = 0; p < ntiles; ++p) {
            bfrag af[4];
            for (int m = 0; m < 4; ++m)
                af[m] = *(const bfrag*)&slab[(16 * m + ml) * SLABW + p * 32 + q * 8];
            bfrag bf_[4];
            const ushort* bp = Bswz + ((size_t)((gbase + p) * NT + (w << 2)) * 64 + l) * 8;
            for (int n = 0; n < 4; ++n)
                bf_[n] = *(const bfrag*)(bp + (size_t)n * 64 * 8);
            for (int m = 0; m < 4; ++m)
                for (int n = 0; n < 4; ++n)
                    acc[m][n] = __builtin_amdgcn_mfma_f32_16x16x32_bf16(af[m], bf_[n], acc[m][n], 0, 0, 0);
        }
    };

    const int r  = t >> 3;            // staging row 0..63 (sinemb phases)
    const int c0 = (t & 7) * 4;       // staging col 0..28 step 4

    // ---- GEMM1: 4 phases over KE ----
    load_rows_gather(ssrc);              __syncthreads();
    kloop(w1s, 16, 0);                   __syncthreads();
    load_rows_gather(sdst);              __syncthreads();
    kloop(w1s, 16, 16);                  __syncthreads();
    {
        float fx = sfd[r * 3 + 0], fy = sfd[r * 3 + 1], fz = sfd[r * 3 + 2];
        // phase C1: lat(32 cols incl pad) + sin(384) = 13 ktiles
        for (int i = 0; i < 13; ++i) {
            int c = c0 + 32 * i;
            float f[4];
            if (c < 32) {
                for (int ii = 0; ii < 4; ++ii) {
                    int cc = c + ii;
                    f[ii] = (cc < 6) ? slat[r * 6 + cc] : 0.0f;
                }
            } else {
                int d = c - 32;                    // 0..383
                int dim = d >> 7;
                float x = (dim == 0) ? fx : (dim == 1) ? fy : fz;
                float base = (float)(d & 127) * x;
                for (int ii = 0; ii < 4; ++ii)
                    f[ii] = __builtin_amdgcn_sinf(__builtin_amdgcn_fractf(base + (float)ii * x));
            }
            ushort4 v = make_ushort4(f2bf(f[0]), f2bf(f[1]), f2bf(f[2]), f2bf(f[3]));
            *(ushort4*)&slab[r * SLABW + c] = v;
        }
        __syncthreads();
        kloop(w1s, 13, 32);              __syncthreads();
        // phase C2: cos(384) = 12 ktiles
        for (int i = 0; i < 12; ++i) {
            int c = c0 + 32 * i;                   // 0..383
            int dim = c >> 7;
            float x = (dim == 0) ? fx : (dim == 1) ? fy : fz;
            float base = (float)(c & 127) * x;
            float f[4];
            for (int ii = 0; ii < 4; ++ii)
                f[ii] = __builtin_amdgcn_cosf(__builtin_amdgcn_fractf(base + (float)ii * x));
            ushort4 v = make_ushort4(f2bf(f[0]), f2bf(f[1]), f2bf(f[2]), f2bf(f[3]));
            *(ushort4*)&slab[r * SLABW + c] = v;
        }
        __syncthreads();
        kloop(w1s, 12, 45);
    }

    // ---- e1 = silu(acc + b1) -> slab (bf16, row-major) ----
    __syncthreads();                      // all slab reads of last kloop done
    for (int n = 0; n < 4; ++n) {
        int cg = w * 64 + n * 16 + ml;
        float bv = b1[cg];
        for (int m = 0; m < 4; ++m)
            for (int rr = 0; rr < 4; ++rr) {
                int rowl = 16 * m + 4 * q + rr;
                slab[rowl * SLABW + cg] = f2bf(silu_f(acc[m][n][rr] + bv));
            }
    }
    // reset acc for GEMM2
    for (int m = 0; m < 4; ++m)
        for (int n = 0; n < 4; ++n)
            acc[m][n] = (ffrag){0.0f, 0.0f, 0.0f, 0.0f};
    __syncthreads();

    // ---- GEMM2 straight from the slab ----
    kloop(w2s, 16, 0);

    // ---- silu + CSR run-length segment reduce -> atomic agg ----
    float* fs = (float*)slab;            // 64 x 256 fp32 = 65536 B
    for (int hh = 0; hh < 2; ++hh) {
        __syncthreads();
        if ((w >> 2) == hh) {
            for (int n = 0; n < 4; ++n) {
                int cg = w * 64 + n * 16 + ml;
                int lc = cg - hh * 256;
                float bv = b2[cg];
                for (int m = 0; m < 4; ++m)
                    for (int rr = 0; rr < 4; ++rr) {
                        int rowl = 16 * m + 4 * q + rr;
                        fs[rowl * 256 + lc] = silu_f(acc[m][n][rr] + bv);
                    }
            }
        }
        __syncthreads();
        if (t < 256) {
            int col = hh * 256 + t;
            int cur = ssrc[0];
            float run = 0.f;
            for (int rr2 = 0; rr2 < 64; ++rr2) {
                int nd = ssrc[rr2];
                if (nd != cur) {
                    unsafeAtomicAdd(&agg[(size_t)cur * HD + col], run);
                    run = 0.f; cur = nd;
                }
                run += fs[rr2 * 256 + t];
            }
            unsafeAtomicAdd(&agg[(size_t)cur * HD + col], run);
        }
    }
}

// ---------------- Fused node MLP (64 nodes x 512 cols per block) ------------
// A = [h | aggb] -> silu -> slab -> GEMM2 -> out = nf + silu
__global__ __launch_bounds__(512, 4) void node_mlp(
    const ushort* __restrict__ h,     const ushort* __restrict__ aggb,
    const ushort* __restrict__ wn1s,  const ushort* __restrict__ wn2s,
    const float* __restrict__ b1,     const float* __restrict__ b2,
    const float* __restrict__ nf,     float* __restrict__ out) {

    __shared__ __align__(16) ushort slab[64 * SLABW];

    const int t = threadIdx.x;        // 512 threads = 8 waves
    const int w = t >> 6;
    const int l = t & 63;
    const int q = l >> 4;
    const int ml = l & 15;
    const int rowbase = blockIdx.x * 64;

    ffrag acc[4][4];
    for (int m = 0; m < 4; ++m)
        for (int n = 0; n < 4; ++n)
            acc[m][n] = (ffrag){0.0f, 0.0f, 0.0f, 0.0f};

    auto load_rows_lin = [&](const ushort* base) {
        for (int j = 0; j < 8; ++j) {
            int r = w * 8 + j;
            int row = rowbase + r;
            if (row >= N_NODES) row = N_NODES - 1;
            const ushort* gp = base + (size_t)row * HD + l * 8;
            gll16(gp, &slab[r * SLABW]);
        }
    };
    auto kloop = [&](const ushort* Bswz, int ntiles, int gbase) {
        for (int p = 0; p < ntiles; ++p) {
            bfrag af[4];
            for (int m = 0; m < 4; ++m)
                af[m] = *(const bfrag*)&slab[(16 * m + ml) * SLABW + p * 32 + q * 8];
            bfrag bf_[4];
            const ushort* bp = Bswz + ((size_t)((gbase + p) * NT + (w << 2)) * 64 + l) * 8;
            for (int n = 0; n < 4; ++n)
                bf_[n] = *(const bfrag*)(bp + (size_t)n * 64 * 8);
            for (int m = 0; m < 4; ++m)
                for (int n = 0; n < 4; ++n)
                    acc[m][n] = __builtin_amdgcn_mfma_f32_16x16x32_bf16(af[m], bf_[n], acc[m][n], 0, 0, 0);
        }
    };

    load_rows_lin(h);                    __syncthreads();
    kloop(wn1s, 16, 0);                  __syncthreads();
    load_rows_lin(aggb);                 __syncthreads();
    kloop(wn1s, 16, 16);                 __syncthreads();

    // o1 = silu(acc + b1) -> slab
    for (int n = 0; n < 4; ++n) {
        int cg = w * 64 + n * 16 + ml;
        float bv = b1[cg];
        for (int m = 0; m < 4; ++m)
            for (int rr = 0; rr < 4; ++rr) {
                int rowl = 16 * m + 4 * q + rr;
                slab[rowl * SLABW + cg] = f2bf(silu_f(acc[m][n][rr] + bv));
            }
    }
    for (int m = 0; m < 4; ++m)
        for (int n = 0; n < 4; ++n)
            acc[m][n] = (ffrag){0.0f, 0.0f, 0.0f, 0.0f};
    __syncthreads();

    kloop(wn2s, 16, 0);

    for (int n = 0; n < 4; ++n) {
        int cg = w * 64 + n * 16 + ml;
        float bv = b2[cg];
        for (int m = 0; m < 4; ++m)
            for (int rr = 0; rr < 4; ++rr) {
                int rowl = 16 * m + 4 * q + rr;
                int row = rowbase + rowl;
                if (row < N_NODES) {
                    float v = silu_f(acc[m][n][rr] + bv);
                    out[(size_t)row * HD + cg] = nf[(size_t)row * HD + cg] + v;
                }
            }
    }
}

// ---------------------------------------------------------------------------
extern "C" void kernel_launch(void* const* d_in, const int* in_sizes, int n_in,
                              void* d_out, int out_size, void* d_ws, size_t ws_size,
                              hipStream_t stream) {
    const float* nf      = (const float*)d_in[0];
    const float* latt    = (const float*)d_in[1];
    const int*   eidx    = (const int*)d_in[2];
    const int*   e2g     = (const int*)d_in[3];
    const float* fd      = (const float*)d_in[4];
    const float* ln_g    = (const float*)d_in[6];
    const float* ln_b    = (const float*)d_in[7];
    const float* W_e1    = (const float*)d_in[8];
    const float* b_e1    = (const float*)d_in[9];
    const float* W_e2    = (const float*)d_in[10];
    const float* b_e2    = (const float*)d_in[11];
    const float* W_n1    = (const float*)d_in[12];
    const float* b_n1    = (const float*)d_in[13];
    const float* W_n2    = (const float*)d_in[14];
    const float* b_n2    = (const float*)d_in[15];
    float* out = (float*)d_out;

    auto al = [](size_t x) { return (x + 511) & ~(size_t)511; };
    size_t off_h    = 0;                         size_t sz_h    = (size_t)N_NODES * HD * 2;
    size_t off_w1   = al(off_h + sz_h);          size_t sz_w1   = (size_t)KE * HD * 2;
    size_t off_w2   = al(off_w1 + sz_w1);        size_t sz_w2   = (size_t)HD * HD * 2;
    size_t off_wn1  = al(off_w2 + sz_w2);        size_t sz_wn1  = (size_t)2 * HD * HD * 2;
    size_t off_wn2  = al(off_wn1 + sz_wn1);      size_t sz_wn2  = (size_t)HD * HD * 2;
    size_t off_agb  = al(off_wn2 + sz_wn2);      size_t sz_agb  = (size_t)N_NODES * HD * 2;
    size_t off_c32  = al(off_agb + sz_agb);      size_t sz_c32  = (size_t)N_NODES * 4;
    size_t off_cur  = al(off_c32 + sz_c32);      size_t sz_cur  = (size_t)N_NODES * 4;
    size_t off_rp   = al(off_cur + sz_cur);      size_t sz_rp   = (size_t)(N_NODES + 1) * 4;
    size_t off_ebuf = al(off_rp + sz_rp);        size_t sz_ebuf = (size_t)N_EDGES * 4;
    size_t off_agg  = al(off_ebuf + sz_ebuf);    size_t sz_agg  = (size_t)N_NODES * HD * 4;
    size_t need     = off_agg + sz_agg;

    if (ws_size < need) {
        sentinel_kernel<<<(out_size + 255) / 256, 256, 0, stream>>>(out, out_size);
        return;
    }

    char* ws = (char*)d_ws;
    ushort* h    = (ushort*)(ws + off_h);
    ushort* w1s  = (ushort*)(ws + off_w1);
    ushort* w2s  = (ushort*)(ws + off_w2);
    ushort* wn1s = (ushort*)(ws + off_wn1);
    ushort* wn2s = (ushort*)(ws + off_wn2);
    ushort* aggb = (ushort*)(ws + off_agb);
    int*    c32  = (int*)(ws + off_c32);
    int*    cur  = (int*)(ws + off_cur);
    int*    rp   = (int*)(ws + off_rp);
    int*    ebuf = (int*)(ws + off_ebuf);
    float*  agg  = (float*)(ws + off_agg);

    // prep
    ln_kernel<<<N_NODES, 256, 0, stream>>>(nf, ln_g, ln_b, h);
    wswz_kernel<<<(KE / 32) * NT * 64 / 256, 256, 0, stream>>>(W_e1, w1s, KE, 1);
    wswz_kernel<<<(HD / 32) * NT * 64 / 256, 256, 0, stream>>>(W_e2, w2s, HD, 0);
    wswz_kernel<<<(2 * HD / 32) * NT * 64 / 256, 256, 0, stream>>>(W_n1, wn1s, 2 * HD, 0);
    wswz_kernel<<<(HD / 32) * NT * 64 / 256, 256, 0, stream>>>(W_n2, wn2s, HD, 0);
    hipMemsetAsync(c32, 0, sz_c32, stream);
    hipMemsetAsync(agg, 0, sz_agg, stream);

    // CSR build (edges sorted by src node)
    hist_kernel<<<(N_EDGES + 255) / 256, 256, 0, stream>>>(eidx, c32);
    scan_kernel<<<1, 1024, 0, stream>>>(c32, rp, cur);
    csr_fill<<<(N_EDGES + 255) / 256, 256, 0, stream>>>(eidx, cur, ebuf);

    // fused edge MLP (CSR order) -> agg
    edge_mlp<<<N_EDGES / 64, 512, 0, stream>>>(
        h, w1s, w2s, b_e1, b_e2, agg, eidx, e2g, latt, fd, ebuf);

    // scatter-mean divide (deg from CSR)
    aggdiv_kernel<<<(N_NODES * HD) / 256, 256, 0, stream>>>(agg, rp, aggb);

    // fused node MLP
    int nblocks = (N_NODES + 63) / 64;
    node_mlp<<<nblocks, 512, 0, stream>>>(h, aggb, wn1s, wn2s, b_n1, b_n2, nf, out);
}